// Round 5
// baseline (1542.956 us; speedup 1.0000x reference)
//
#include <hip/hip_runtime.h>

#define NN 100000
#define NE 1600000
#define DIM 128
#define NA 5
#define STEPS 5

// fixed-point packing for coeff atomics
#define CSCALE 1048576.0f            // 2^20
#define CINV   9.5367431640625e-07f  // 2^-20

typedef float vf2 __attribute__((ext_vector_type(2)));
typedef float f32x4 __attribute__((ext_vector_type(4)));
typedef short short8v __attribute__((ext_vector_type(8)));

__device__ __forceinline__ float wsum(float v) {
#pragma unroll
  for (int off = 32; off > 0; off >>= 1) v += __shfl_xor(v, off, 64);
  return v;
}

// pack two f32 into one u32 of 2 bf16 (truncation): low16 = bf16(a), high16 = bf16(b)
__device__ __forceinline__ unsigned pkhi(float a, float b) {
  return __builtin_amdgcn_perm(__float_as_uint(b), __float_as_uint(a),
                               0x07060302u);
}
// residual after bf16 truncation
__device__ __forceinline__ float lof(float x) {
  return x - __uint_as_float(__float_as_uint(x) & 0xffff0000u);
}

// ---- prep: M = edge_anchor @ W1b.T ----
__global__ __launch_bounds__(128) void k_prepM(
    const float* __restrict__ W1, const float* __restrict__ edge_anchor,
    float* __restrict__ M) {
  const int i = threadIdx.x;
  const int a = blockIdx.x;
  float s = 0.f;
  for (int j = 0; j < DIM; ++j)
    s = fmaf(edge_anchor[a * DIM + j], W1[i * 2 * DIM + DIM + j], s);
  M[a * DIM + i] = s;
}

// ---- pack W1 (A-frags, native) and W2 (A-frags with sigma/tau permutation)
// layout: wp[((mat*2+part)*32 + nf*4+ks)*64 + lane], 16B each (8 bf16)
__global__ __launch_bounds__(256) void k_wpack(
    const float* __restrict__ W1, const float* __restrict__ W2,
    uint4* __restrict__ wp) {
  const int mat = blockIdx.x >> 3, nf = blockIdx.x & 7;
  const int ks = threadIdx.x >> 6, lane = threadIdx.x & 63;
  const int g = lane >> 4, r = lane & 15;
  float v[8];
  if (mat == 0) {
    // A[16nf+r][32ks+8g+j] = W1a[row][col] = W1[row*256 + col]
    const float* src = W1 + (16 * nf + r) * 256 + 32 * ks + 8 * g;
    float4 a = *(const float4*)src;
    float4 b = *(const float4*)(src + 4);
    v[0] = a.x; v[1] = a.y; v[2] = a.z; v[3] = a.w;
    v[4] = b.x; v[5] = b.y; v[6] = b.z; v[7] = b.w;
  } else {
    // A'[16nf+r][32ks+8g+j] = W2[tau(16nf+r)][sigma(32ks+8g+j)]
    // tau = 32*(nf>>1) + 8*(r>>2) + 4*(nf&1) + (r&3)
    // sigma = 32ks + 16*(j>>2) + 4g + (j&3)
    const int trow = 32 * (nf >> 1) + 8 * (r >> 2) + 4 * (nf & 1) + (r & 3);
    const float* src = W2 + trow * 128 + 32 * ks + 4 * g;
    float4 a = *(const float4*)src;         // j=0..3
    float4 b = *(const float4*)(src + 16);  // j=4..7
    v[0] = a.x; v[1] = a.y; v[2] = a.z; v[3] = a.w;
    v[4] = b.x; v[5] = b.y; v[6] = b.z; v[7] = b.w;
  }
  unsigned h[4], l[4];
#pragma unroll
  for (int w = 0; w < 4; ++w) {
    h[w] = pkhi(v[2 * w], v[2 * w + 1]);
    l[w] = pkhi(lof(v[2 * w]), lof(v[2 * w + 1]));
  }
  wp[((mat * 2 + 0) * 32 + nf * 4 + ks) * 64 + lane] =
      make_uint4(h[0], h[1], h[2], h[3]);
  wp[((mat * 2 + 1) * 32 + nf * 4 + ks) * 64 + lane] =
      make_uint4(l[0], l[1], l[2], l[3]);
}

// ---- node pre-pass: att softmax + node_x, and p1/p2 edge projections ----
__global__ __launch_bounds__(256) void k_node(
    const float* __restrict__ x, const float* __restrict__ W_att,
    const float* __restrict__ b_att, const float* __restrict__ node_anchor,
    const float* __restrict__ W_edge, const float* __restrict__ b_edge,
    float* __restrict__ node_x, float* __restrict__ p12) {
  const int wid = threadIdx.x >> 6, lane = threadIdx.x & 63;
  const int d0 = lane << 1;
  float wa0[NA], wa1[NA], we10[NA], we11[NA], we20[NA], we21[NA];
  float na0[NA], na1[NA], ba[NA], be[NA];
#pragma unroll
  for (int a = 0; a < NA; ++a) {
    wa0[a] = W_att[a * DIM + d0];
    wa1[a] = W_att[a * DIM + d0 + 1];
    we10[a] = W_edge[a * 2 * DIM + d0];
    we11[a] = W_edge[a * 2 * DIM + d0 + 1];
    we20[a] = W_edge[a * 2 * DIM + DIM + d0];
    we21[a] = W_edge[a * 2 * DIM + DIM + d0 + 1];
    na0[a] = node_anchor[a * DIM + d0];
    na1[a] = node_anchor[a * DIM + d0 + 1];
    ba[a] = b_att[a];
    be[a] = b_edge[a];
  }
  const int stride = gridDim.x << 2;
  for (int n = (blockIdx.x << 2) + wid; n < NN; n += stride) {
    float2 xv = *(const float2*)(x + (size_t)n * DIM + d0);
    float att[NA], p1[NA], p2[NA];
#pragma unroll
    for (int a = 0; a < NA; ++a) {
      att[a] = wsum(xv.x * wa0[a] + xv.y * wa1[a]) + ba[a];
      p1[a] = wsum(xv.x * we10[a] + xv.y * we11[a]) + be[a];
      p2[a] = wsum(xv.x * we20[a] + xv.y * we21[a]);
    }
    float m = fmaxf(fmaxf(fmaxf(att[0], att[1]), fmaxf(att[2], att[3])), att[4]);
    float s = 0.f;
#pragma unroll
    for (int a = 0; a < NA; ++a) { att[a] = expf(att[a] - m); s += att[a]; }
    float inv = 1.f / s;
    float2 nx = xv;
#pragma unroll
    for (int a = 0; a < NA; ++a) {
      float w = att[a] * inv;
      nx.x = fmaf(w, na0[a], nx.x);
      nx.y = fmaf(w, na1[a], nx.y);
    }
    *(float2*)(node_x + (size_t)n * DIM + d0) = nx;
    if (lane < NA) {
      float v1 = p1[0], v2 = p2[0];
#pragma unroll
      for (int a = 1; a < NA; ++a)
        if (lane == a) { v1 = p1[a]; v2 = p2[a]; }
      p12[(size_t)n * 12 + lane] = v1;
      p12[(size_t)n * 12 + 6 + lane] = v2;
    }
  }
}

__device__ __forceinline__ void edge_b(const float* __restrict__ p12, int src,
                                       int dst, float* __restrict__ b) {
  float4 q1 = *(const float4*)(p12 + (size_t)src * 12);
  float p14 = p12[(size_t)src * 12 + 4];
  float2 r0 = *(const float2*)(p12 + (size_t)dst * 12 + 6);
  float2 r1 = *(const float2*)(p12 + (size_t)dst * 12 + 8);
  float p24 = p12[(size_t)dst * 12 + 10];
  float l[NA] = {q1.x + r0.x, q1.y + r0.y, q1.z + r1.x, q1.w + r1.y,
                 p14 + p24};
#pragma unroll
  for (int a = 0; a < NA; ++a) l[a] = l[a] >= 0.f ? l[a] : 0.01f * l[a];
  float m = fmaxf(fmaxf(fmaxf(l[0], l[1]), fmaxf(l[2], l[3])), l[4]);
  float s = 0.f;
#pragma unroll
  for (int a = 0; a < NA; ++a) { l[a] = expf(l[a] - m); s += l[a]; }
  float inv = 1.f / s;
#pragma unroll
  for (int a = 0; a < NA; ++a) b[a] = l[a] * inv;
}

// ---- coeff pass: pure atomics, fixed-point packed u64 (3 per endpoint) ----
__global__ __launch_bounds__(256) void k_coeff(
    const int* __restrict__ ei, const float* __restrict__ p12,
    unsigned long long* __restrict__ coeffp) {
  const int e = blockIdx.x * 256 + threadIdx.x;
  const int src = ei[e], dst = ei[NE + e];
  float b[NA];
  edge_b(p12, src, dst, b);
  unsigned q[NA];
#pragma unroll
  for (int a = 0; a < NA; ++a) q[a] = (unsigned)fmaf(b[a], CSCALE, 0.5f);
  unsigned long long p01 = (unsigned long long)q[0] |
                           ((unsigned long long)q[1] << 32);
  unsigned long long p23 = (unsigned long long)q[2] |
                           ((unsigned long long)q[3] << 32);
  unsigned long long p4 = (unsigned long long)q[4];
  atomicAdd(coeffp + (size_t)src * 3 + 0, p01);
  atomicAdd(coeffp + (size_t)src * 3 + 1, p23);
  atomicAdd(coeffp + (size_t)src * 3 + 2, p4);
  atomicAdd(coeffp + (size_t)dst * 3 + 0, p01);
  atomicAdd(coeffp + (size_t)dst * 3 + 1, p23);
  atomicAdd(coeffp + (size_t)dst * 3 + 2, p4);
}

// ---- ep pass: edge_prompt stream-out, no atomics, no __syncthreads ----
__global__ __launch_bounds__(256) void k_ep(
    const int* __restrict__ ei, const float* __restrict__ p12,
    const float* __restrict__ edge_anchor, float* __restrict__ ep) {
  __shared__ float bs[4][64][8];
  const int t = threadIdx.x;
  const int w = t >> 6, lane = t & 63, d0 = lane << 1;
  const int e = blockIdx.x * 256 + t;
  {
    float b[NA];
    edge_b(p12, ei[e], ei[NE + e], b);
    *(float4*)&bs[w][lane][0] = make_float4(b[0], b[1], b[2], b[3]);
    bs[w][lane][4] = b[4];
  }
  float ea0[NA], ea1[NA];
#pragma unroll
  for (int a = 0; a < NA; ++a) {
    ea0[a] = edge_anchor[a * DIM + d0];
    ea1[a] = edge_anchor[a * DIM + d0 + 1];
  }
  const size_t ebase = (size_t)blockIdx.x * 256 + ((size_t)w << 6);
#pragma unroll 2
  for (int k = 0; k < 64; ++k) {
    float4 c = *(const float4*)&bs[w][k][0];
    float c4 = bs[w][k][4];
    vf2 v;
    v[0] = c.x * ea0[0] + c.y * ea0[1] + c.z * ea0[2] + c.w * ea0[3] +
           c4 * ea0[4];
    v[1] = c.x * ea1[0] + c.y * ea1[1] + c.z * ea1[2] + c.w * ea1[3] +
           c4 * ea1[4];
    __builtin_nontemporal_store(v, (vf2*)(ep + (ebase + k) * DIM + d0));
  }
}

// ---- ODE via MFMA, split-bf16 (hi+lo), transposed matvecs, zero shuffles ----
// Per wave: 16 nodes (node = m0 + (lane&15), lane-local). State EV in "frag
// layout": evr[ks][j] = EV[node][32ks+8g+j], g = lane>>4.
// mv1: H^T = W1a x EV^T (A = packed W1 frags, B = evr directly).
// mv2: Y^T = W2' x H^T with W2 packed under sigma (K-enum) and tau (row-enum)
// so B-frags are mv1's packed output pairs and the output maps 1:1 onto evr.
__global__ __launch_bounds__(512, 2) void k_ode(
    const unsigned long long* __restrict__ coeffp, const float* __restrict__ M,
    const uint4* __restrict__ wp, const float* __restrict__ b1,
    const float* __restrict__ b2, float* __restrict__ ev) {
  __shared__ uint4 wl[2][2][32][64];  // [mat][part][nf*4+ks][lane] = 128 KB
  const int tid = threadIdx.x;
  {
    uint4* dst = &wl[0][0][0][0];
#pragma unroll
    for (int i = 0; i < 16; ++i) dst[i * 512 + tid] = wp[i * 512 + tid];
  }
  const int wid = tid >> 6, lane = tid & 63;
  const int g = lane >> 4, r = lane & 15;
  const int node = blockIdx.x * 128 + wid * 16 + r;
  const bool ok = node < NN;

  float evr[4][8];
#pragma unroll
  for (int ks = 0; ks < 4; ++ks) {
    float4 a = make_float4(0.f, 0.f, 0.f, 0.f), b = a;
    if (ok) {
      const float* p = ev + (size_t)node * DIM + 32 * ks + 8 * g;
      a = *(const float4*)p;
      b = *(const float4*)(p + 4);
    }
    evr[ks][0] = a.x; evr[ks][1] = a.y; evr[ks][2] = a.z; evr[ks][3] = a.w;
    evr[ks][4] = b.x; evr[ks][5] = b.y; evr[ks][6] = b.z; evr[ks][7] = b.w;
  }
  float c[NA] = {0.f, 0.f, 0.f, 0.f, 0.f};
  if (ok) {
    unsigned long long v0 = coeffp[(size_t)node * 3 + 0];
    unsigned long long v1 = coeffp[(size_t)node * 3 + 1];
    unsigned long long v2 = coeffp[(size_t)node * 3 + 2];
    c[0] = (float)(unsigned)v0 * CINV;
    c[1] = (float)(unsigned)(v0 >> 32) * CINV;
    c[2] = (float)(unsigned)v1 * CINV;
    c[3] = (float)(unsigned)(v1 >> 32) * CINV;
    c[4] = (float)(unsigned)v2 * CINV;
  }
  // agg_proj in C layout: aggp[nf][i] = b1[col] + sum_a c[a]*M[a][col],
  // col = 16nf + 4g + i
  f32x4 aggp[8];
#pragma unroll
  for (int nf = 0; nf < 8; ++nf) {
    float4 bb = *(const float4*)(b1 + 16 * nf + 4 * g);
    f32x4 s = {bb.x, bb.y, bb.z, bb.w};
#pragma unroll
    for (int a = 0; a < NA; ++a) {
      float4 mm = *(const float4*)(M + a * DIM + 16 * nf + 4 * g);
      s[0] = fmaf(c[a], mm.x, s[0]);
      s[1] = fmaf(c[a], mm.y, s[1]);
      s[2] = fmaf(c[a], mm.z, s[2]);
      s[3] = fmaf(c[a], mm.w, s[3]);
    }
    aggp[nf] = s;
  }
  const float dt = 1.f / STEPS;
  float dtb2[4][8];
#pragma unroll
  for (int ks = 0; ks < 4; ++ks) {
    const float* p = b2 + 32 * ks + 8 * g;
    float4 a = *(const float4*)p;
    float4 b = *(const float4*)(p + 4);
    dtb2[ks][0] = dt * a.x; dtb2[ks][1] = dt * a.y;
    dtb2[ks][2] = dt * a.z; dtb2[ks][3] = dt * a.w;
    dtb2[ks][4] = dt * b.x; dtb2[ks][5] = dt * b.y;
    dtb2[ks][6] = dt * b.z; dtb2[ks][7] = dt * b.w;
  }
  __syncthreads();

#pragma unroll 1
  for (int step = 0; step < STEPS; ++step) {
    // pack EV -> B-frags (hi/lo)
    short8v Bh[4], Bl[4];
#pragma unroll
    for (int ks = 0; ks < 4; ++ks) {
      union { unsigned u[4]; short8v s; } qh, ql;
#pragma unroll
      for (int w = 0; w < 4; ++w) {
        float x0 = evr[ks][2 * w], x1 = evr[ks][2 * w + 1];
        qh.u[w] = pkhi(x0, x1);
        ql.u[w] = pkhi(lof(x0), lof(x1));
      }
      Bh[ks] = qh.s;
      Bl[ks] = ql.s;
    }
    // mv1: acc[nf] = H^T tile (C layout), init with agg_proj
    f32x4 acc[8];
#pragma unroll
    for (int nf = 0; nf < 8; ++nf) acc[nf] = aggp[nf];
#pragma unroll
    for (int ks = 0; ks < 4; ++ks)
#pragma unroll
      for (int nf = 0; nf < 8; ++nf) {
        short8v wh = *(const short8v*)&wl[0][0][nf * 4 + ks][lane];
        short8v wo = *(const short8v*)&wl[0][1][nf * 4 + ks][lane];
        acc[nf] = __builtin_amdgcn_mfma_f32_16x16x32_bf16(wh, Bh[ks], acc[nf], 0, 0, 0);
        acc[nf] = __builtin_amdgcn_mfma_f32_16x16x32_bf16(wh, Bl[ks], acc[nf], 0, 0, 0);
        acc[nf] = __builtin_amdgcn_mfma_f32_16x16x32_bf16(wo, Bh[ks], acc[nf], 0, 0, 0);
      }
    // relu + pack H (hi/lo pairs)
    unsigned P0h[8], P1h[8], P0l[8], P1l[8];
#pragma unroll
    for (int nf = 0; nf < 8; ++nf) {
      float h0 = fmaxf(acc[nf][0], 0.f), h1 = fmaxf(acc[nf][1], 0.f);
      float h2 = fmaxf(acc[nf][2], 0.f), h3 = fmaxf(acc[nf][3], 0.f);
      P0h[nf] = pkhi(h0, h1);
      P1h[nf] = pkhi(h2, h3);
      P0l[nf] = pkhi(lof(h0), lof(h1));
      P1l[nf] = pkhi(lof(h2), lof(h3));
    }
    // mv2
    f32x4 acc2[8];
#pragma unroll
    for (int nf = 0; nf < 8; ++nf) acc2[nf] = (f32x4){0.f, 0.f, 0.f, 0.f};
#pragma unroll
    for (int ks = 0; ks < 4; ++ks) {
      union { unsigned u[4]; short8v s; } qh, ql;
      qh.u[0] = P0h[2 * ks]; qh.u[1] = P1h[2 * ks];
      qh.u[2] = P0h[2 * ks + 1]; qh.u[3] = P1h[2 * ks + 1];
      ql.u[0] = P0l[2 * ks]; ql.u[1] = P1l[2 * ks];
      ql.u[2] = P0l[2 * ks + 1]; ql.u[3] = P1l[2 * ks + 1];
      short8v bh = qh.s, bl = ql.s;
#pragma unroll
      for (int nf = 0; nf < 8; ++nf) {
        short8v wh = *(const short8v*)&wl[1][0][nf * 4 + ks][lane];
        short8v wo = *(const short8v*)&wl[1][1][nf * 4 + ks][lane];
        acc2[nf] = __builtin_amdgcn_mfma_f32_16x16x32_bf16(wh, bh, acc2[nf], 0, 0, 0);
        acc2[nf] = __builtin_amdgcn_mfma_f32_16x16x32_bf16(wh, bl, acc2[nf], 0, 0, 0);
        acc2[nf] = __builtin_amdgcn_mfma_f32_16x16x32_bf16(wo, bh, acc2[nf], 0, 0, 0);
      }
    }
    // EV update: tau maps acc2 regs 1:1 onto evr regs
#pragma unroll
    for (int ks = 0; ks < 4; ++ks)
#pragma unroll
      for (int j = 0; j < 8; ++j)
        evr[ks][j] += dt * acc2[2 * ks + (j >> 2)][j & 3] + dtb2[ks][j];
  }
  if (ok) {
#pragma unroll
    for (int ks = 0; ks < 4; ++ks) {
      float* p = ev + (size_t)node * DIM + 32 * ks + 8 * g;
      *(float4*)p = make_float4(evr[ks][0], evr[ks][1], evr[ks][2], evr[ks][3]);
      *(float4*)(p + 4) =
          make_float4(evr[ks][4], evr[ks][5], evr[ks][6], evr[ks][7]);
    }
  }
}

extern "C" void kernel_launch(void* const* d_in, const int* in_sizes, int n_in,
                              void* d_out, int out_size, void* d_ws,
                              size_t ws_size, hipStream_t stream) {
  const float* x = (const float*)d_in[0];
  const int* ei = (const int*)d_in[1];
  const float* node_anchor = (const float*)d_in[2];
  const float* W_att = (const float*)d_in[3];
  const float* b_att = (const float*)d_in[4];
  const float* edge_anchor = (const float*)d_in[5];
  const float* W_edge = (const float*)d_in[6];
  const float* b_edge = (const float*)d_in[7];
  const float* W1 = (const float*)d_in[8];
  const float* b1 = (const float*)d_in[9];
  const float* W2 = (const float*)d_in[10];
  const float* b2 = (const float*)d_in[11];

  float* out = (float*)d_out;
  float* ev = out;                     // N*DIM (node_x staged here, then ev)
  float* ep = out + (size_t)NN * DIM;  // E*DIM edge_prompt

  char* ws = (char*)d_ws;
  float* p12 = (float*)(ws);  // N*12 floats = 4.8 MB
  unsigned long long* coeffp =
      (unsigned long long*)(ws + 4800000);   // N*3 u64 = 2.4 MB
  float* Mm = (float*)(ws + 7200000);        // 5*128 floats
  uint4* wpack = (uint4*)(ws + 7202560);     // 128 KB packed W frags

  hipMemsetAsync(coeffp, 0, (size_t)NN * 3 * sizeof(unsigned long long),
                 stream);
  k_prepM<<<NA, DIM, 0, stream>>>(W1, edge_anchor, Mm);
  k_wpack<<<16, 256, 0, stream>>>(W1, W2, wpack);
  k_node<<<2048, 256, 0, stream>>>(x, W_att, b_att, node_anchor, W_edge, b_edge,
                                   ev, p12);
  k_coeff<<<NE / 256, 256, 0, stream>>>(ei, p12, coeffp);
  k_ep<<<NE / 256, 256, 0, stream>>>(ei, p12, edge_anchor, ep);
  k_ode<<<(NN + 127) / 128, 512, 0, stream>>>(coeffp, Mm, wpack, b1, b2, ev);
}

// Round 6
// 1410.309 us; speedup vs baseline: 1.0941x; 1.0941x over previous
//
#include <hip/hip_runtime.h>

#define NN 100000
#define NE 1600000
#define DIM 128
#define NA 5
#define STEPS 5

// fixed-point packing for coeff atomics
#define CSCALE 1048576.0f            // 2^20
#define CINV   9.5367431640625e-07f  // 2^-20

typedef float f32x4 __attribute__((ext_vector_type(4)));
typedef short short8v __attribute__((ext_vector_type(8)));

__device__ __forceinline__ float wsum(float v) {
#pragma unroll
  for (int off = 32; off > 0; off >>= 1) v += __shfl_xor(v, off, 64);
  return v;
}

// pack two f32 into one u32 of 2 bf16 (truncation): low16 = bf16(a), high16 = bf16(b)
__device__ __forceinline__ unsigned pkhi(float a, float b) {
  return __builtin_amdgcn_perm(__float_as_uint(b), __float_as_uint(a),
                               0x07060302u);
}
// residual after bf16 truncation
__device__ __forceinline__ float lof(float x) {
  return x - __uint_as_float(__float_as_uint(x) & 0xffff0000u);
}

// ---- prep: M = edge_anchor @ W1b.T ----
__global__ __launch_bounds__(128) void k_prepM(
    const float* __restrict__ W1, const float* __restrict__ edge_anchor,
    float* __restrict__ M) {
  const int i = threadIdx.x;
  const int a = blockIdx.x;
  float s = 0.f;
  for (int j = 0; j < DIM; ++j)
    s = fmaf(edge_anchor[a * DIM + j], W1[i * 2 * DIM + DIM + j], s);
  M[a * DIM + i] = s;
}

// ---- pack W1 (A-frags, native) and W2 (A-frags with sigma/tau permutation)
// layout: wp[((mat*2+part)*32 + nf*4+ks)*64 + lane], 16B each (8 bf16)
__global__ __launch_bounds__(256) void k_wpack(
    const float* __restrict__ W1, const float* __restrict__ W2,
    uint4* __restrict__ wp) {
  const int mat = blockIdx.x >> 3, nf = blockIdx.x & 7;
  const int ks = threadIdx.x >> 6, lane = threadIdx.x & 63;
  const int g = lane >> 4, r = lane & 15;
  float v[8];
  if (mat == 0) {
    // A[16nf+r][32ks+8g+j] = W1a[row][col] = W1[row*256 + col]
    const float* src = W1 + (16 * nf + r) * 256 + 32 * ks + 8 * g;
    float4 a = *(const float4*)src;
    float4 b = *(const float4*)(src + 4);
    v[0] = a.x; v[1] = a.y; v[2] = a.z; v[3] = a.w;
    v[4] = b.x; v[5] = b.y; v[6] = b.z; v[7] = b.w;
  } else {
    // A'[16nf+r][32ks+8g+j] = W2[tau(16nf+r)][sigma(32ks+8g+j)]
    // tau = 32*(nf>>1) + 8*(r>>2) + 4*(nf&1) + (r&3)
    // sigma = 32ks + 16*(j>>2) + 4g + (j&3)
    const int trow = 32 * (nf >> 1) + 8 * (r >> 2) + 4 * (nf & 1) + (r & 3);
    const float* src = W2 + trow * 128 + 32 * ks + 4 * g;
    float4 a = *(const float4*)src;         // j=0..3
    float4 b = *(const float4*)(src + 16);  // j=4..7
    v[0] = a.x; v[1] = a.y; v[2] = a.z; v[3] = a.w;
    v[4] = b.x; v[5] = b.y; v[6] = b.z; v[7] = b.w;
  }
  unsigned h[4], l[4];
#pragma unroll
  for (int w = 0; w < 4; ++w) {
    h[w] = pkhi(v[2 * w], v[2 * w + 1]);
    l[w] = pkhi(lof(v[2 * w]), lof(v[2 * w + 1]));
  }
  wp[((mat * 2 + 0) * 32 + nf * 4 + ks) * 64 + lane] =
      make_uint4(h[0], h[1], h[2], h[3]);
  wp[((mat * 2 + 1) * 32 + nf * 4 + ks) * 64 + lane] =
      make_uint4(l[0], l[1], l[2], l[3]);
}

// ---- node pre-pass: att softmax + node_x, and p1/p2 edge projections ----
__global__ __launch_bounds__(256) void k_node(
    const float* __restrict__ x, const float* __restrict__ W_att,
    const float* __restrict__ b_att, const float* __restrict__ node_anchor,
    const float* __restrict__ W_edge, const float* __restrict__ b_edge,
    float* __restrict__ node_x, float* __restrict__ p12) {
  const int wid = threadIdx.x >> 6, lane = threadIdx.x & 63;
  const int d0 = lane << 1;
  float wa0[NA], wa1[NA], we10[NA], we11[NA], we20[NA], we21[NA];
  float na0[NA], na1[NA], ba[NA], be[NA];
#pragma unroll
  for (int a = 0; a < NA; ++a) {
    wa0[a] = W_att[a * DIM + d0];
    wa1[a] = W_att[a * DIM + d0 + 1];
    we10[a] = W_edge[a * 2 * DIM + d0];
    we11[a] = W_edge[a * 2 * DIM + d0 + 1];
    we20[a] = W_edge[a * 2 * DIM + DIM + d0];
    we21[a] = W_edge[a * 2 * DIM + DIM + d0 + 1];
    na0[a] = node_anchor[a * DIM + d0];
    na1[a] = node_anchor[a * DIM + d0 + 1];
    ba[a] = b_att[a];
    be[a] = b_edge[a];
  }
  const int stride = gridDim.x << 2;
  for (int n = (blockIdx.x << 2) + wid; n < NN; n += stride) {
    float2 xv = *(const float2*)(x + (size_t)n * DIM + d0);
    float att[NA], p1[NA], p2[NA];
#pragma unroll
    for (int a = 0; a < NA; ++a) {
      att[a] = wsum(xv.x * wa0[a] + xv.y * wa1[a]) + ba[a];
      p1[a] = wsum(xv.x * we10[a] + xv.y * we11[a]) + be[a];
      p2[a] = wsum(xv.x * we20[a] + xv.y * we21[a]);
    }
    float m = fmaxf(fmaxf(fmaxf(att[0], att[1]), fmaxf(att[2], att[3])), att[4]);
    float s = 0.f;
#pragma unroll
    for (int a = 0; a < NA; ++a) { att[a] = expf(att[a] - m); s += att[a]; }
    float inv = 1.f / s;
    float2 nx = xv;
#pragma unroll
    for (int a = 0; a < NA; ++a) {
      float w = att[a] * inv;
      nx.x = fmaf(w, na0[a], nx.x);
      nx.y = fmaf(w, na1[a], nx.y);
    }
    *(float2*)(node_x + (size_t)n * DIM + d0) = nx;
    if (lane < NA) {
      float v1 = p1[0], v2 = p2[0];
#pragma unroll
      for (int a = 1; a < NA; ++a)
        if (lane == a) { v1 = p1[a]; v2 = p2[a]; }
      p12[(size_t)n * 12 + lane] = v1;
      p12[(size_t)n * 12 + 6 + lane] = v2;
    }
  }
}

__device__ __forceinline__ void edge_b(const float* __restrict__ p12, int src,
                                       int dst, float* __restrict__ b) {
  float4 q1 = *(const float4*)(p12 + (size_t)src * 12);
  float p14 = p12[(size_t)src * 12 + 4];
  float2 r0 = *(const float2*)(p12 + (size_t)dst * 12 + 6);
  float2 r1 = *(const float2*)(p12 + (size_t)dst * 12 + 8);
  float p24 = p12[(size_t)dst * 12 + 10];
  float l[NA] = {q1.x + r0.x, q1.y + r0.y, q1.z + r1.x, q1.w + r1.y,
                 p14 + p24};
#pragma unroll
  for (int a = 0; a < NA; ++a) l[a] = l[a] >= 0.f ? l[a] : 0.01f * l[a];
  float m = fmaxf(fmaxf(fmaxf(l[0], l[1]), fmaxf(l[2], l[3])), l[4]);
  float s = 0.f;
#pragma unroll
  for (int a = 0; a < NA; ++a) { l[a] = expf(l[a] - m); s += l[a]; }
  float inv = 1.f / s;
#pragma unroll
  for (int a = 0; a < NA; ++a) b[a] = l[a] * inv;
}

// ---- fused edge pass: coeff atomics + edge_prompt stream-out.
// No __syncthreads (wave-private LDS slice) so atomic latency hides under
// the store stream and we make a single pass over ei/p12.
__global__ __launch_bounds__(256) void k_edge2(
    const int* __restrict__ ei, const float* __restrict__ p12,
    const float* __restrict__ edge_anchor,
    unsigned long long* __restrict__ coeffp, float* __restrict__ ep) {
  __shared__ float bs[4][64][8];
  const int t = threadIdx.x;
  const int w = t >> 6, lane = t & 63;
  const int e = blockIdx.x * 256 + t;
  {
    const int src = ei[e], dst = ei[NE + e];
    float b[NA];
    edge_b(p12, src, dst, b);
    unsigned q[NA];
#pragma unroll
    for (int a = 0; a < NA; ++a) q[a] = (unsigned)fmaf(b[a], CSCALE, 0.5f);
    unsigned long long p01 =
        (unsigned long long)q[0] | ((unsigned long long)q[1] << 32);
    unsigned long long p23 =
        (unsigned long long)q[2] | ((unsigned long long)q[3] << 32);
    unsigned long long p4 = (unsigned long long)q[4];
    atomicAdd(coeffp + (size_t)src * 3 + 0, p01);
    atomicAdd(coeffp + (size_t)src * 3 + 1, p23);
    atomicAdd(coeffp + (size_t)src * 3 + 2, p4);
    atomicAdd(coeffp + (size_t)dst * 3 + 0, p01);
    atomicAdd(coeffp + (size_t)dst * 3 + 1, p23);
    atomicAdd(coeffp + (size_t)dst * 3 + 2, p4);
    // wave-private LDS slice: same-wave DS ops are in-order, no barrier
    *(float4*)&bs[w][lane][0] = make_float4(b[0], b[1], b[2], b[3]);
    bs[w][lane][4] = b[4];
  }
  // 2 edges per iter, float4 (1 KB/wave/instruction) NT stores
  const int esub = lane >> 5, d0 = (lane & 31) << 2;
  float4 ea4[NA];
#pragma unroll
  for (int a = 0; a < NA; ++a)
    ea4[a] = *(const float4*)(edge_anchor + a * DIM + d0);
  const size_t ebase = (size_t)blockIdx.x * 256 + ((size_t)w << 6);
#pragma unroll 2
  for (int k = 0; k < 32; ++k) {
    const int el = 2 * k + esub;
    float4 c = *(const float4*)&bs[w][el][0];
    float c4 = bs[w][el][4];
    f32x4 v;
#pragma unroll
    for (int i = 0; i < 4; ++i) {
      float s = c.x * ((const float*)&ea4[0])[i];
      s = fmaf(c.y, ((const float*)&ea4[1])[i], s);
      s = fmaf(c.z, ((const float*)&ea4[2])[i], s);
      s = fmaf(c.w, ((const float*)&ea4[3])[i], s);
      s = fmaf(c4, ((const float*)&ea4[4])[i], s);
      v[i] = s;
    }
    __builtin_nontemporal_store(v, (f32x4*)(ep + (ebase + el) * DIM + d0));
  }
}

// ---- ODE via MFMA, split-bf16, nf-outer register schedule (no spill) ----
// Per wave: 16 nodes (node lane-local, r = lane&15). State evr[ks][j] =
// EV[node][32ks+8g+j], g = lane>>4.
// mv1: H^T = W1a x EV^T; packed output written directly into mv2's B-frags
// Qh/Ql (slot = compile-time f(nf)). mv2: Y^T = W2' x H^T with W2 packed
// under sigma/tau so output regs map 1:1 onto evr.
__global__ __launch_bounds__(512, 2) void k_ode(
    const unsigned long long* __restrict__ coeffp, const float* __restrict__ M,
    const uint4* __restrict__ wp, const float* __restrict__ b1,
    const float* __restrict__ b2, float* __restrict__ ev) {
  __shared__ uint4 wl[2][2][32][64];  // [mat][part][nf*4+ks][lane] = 128 KB
  __shared__ float b2s[DIM];          // dt * b2
  const int tid = threadIdx.x;
  {
    uint4* dst = &wl[0][0][0][0];
#pragma unroll
    for (int i = 0; i < 16; ++i) dst[i * 512 + tid] = wp[i * 512 + tid];
  }
  if (tid < DIM) b2s[tid] = (1.f / STEPS) * b2[tid];
  const int wid = tid >> 6, lane = tid & 63;
  const int g = lane >> 4, r = lane & 15;
  const int node = blockIdx.x * 128 + wid * 16 + r;
  const bool ok = node < NN;

  float evr[4][8];
#pragma unroll
  for (int ks = 0; ks < 4; ++ks) {
    float4 a = make_float4(0.f, 0.f, 0.f, 0.f), b = a;
    if (ok) {
      const float* p = ev + (size_t)node * DIM + 32 * ks + 8 * g;
      a = *(const float4*)p;
      b = *(const float4*)(p + 4);
    }
    evr[ks][0] = a.x; evr[ks][1] = a.y; evr[ks][2] = a.z; evr[ks][3] = a.w;
    evr[ks][4] = b.x; evr[ks][5] = b.y; evr[ks][6] = b.z; evr[ks][7] = b.w;
  }
  // agg_proj in C layout: aggp[nf][i] = b1[col] + sum_a c[a]*M[a][col],
  // col = 16nf + 4g + i
  f32x4 aggp[8];
  {
    float c[NA] = {0.f, 0.f, 0.f, 0.f, 0.f};
    if (ok) {
      unsigned long long v0 = coeffp[(size_t)node * 3 + 0];
      unsigned long long v1 = coeffp[(size_t)node * 3 + 1];
      unsigned long long v2 = coeffp[(size_t)node * 3 + 2];
      c[0] = (float)(unsigned)v0 * CINV;
      c[1] = (float)(unsigned)(v0 >> 32) * CINV;
      c[2] = (float)(unsigned)v1 * CINV;
      c[3] = (float)(unsigned)(v1 >> 32) * CINV;
      c[4] = (float)(unsigned)v2 * CINV;
    }
#pragma unroll
    for (int nf = 0; nf < 8; ++nf) {
      float4 bb = *(const float4*)(b1 + 16 * nf + 4 * g);
      f32x4 s = {bb.x, bb.y, bb.z, bb.w};
#pragma unroll
      for (int a = 0; a < NA; ++a) {
        float4 mm = *(const float4*)(M + a * DIM + 16 * nf + 4 * g);
        s[0] = fmaf(c[a], mm.x, s[0]);
        s[1] = fmaf(c[a], mm.y, s[1]);
        s[2] = fmaf(c[a], mm.z, s[2]);
        s[3] = fmaf(c[a], mm.w, s[3]);
      }
      aggp[nf] = s;
    }
  }
  __syncthreads();
  const float dt = 1.f / STEPS;

  typedef union { unsigned u[4]; short8v s; } frag_u;
#pragma unroll 1
  for (int step = 0; step < STEPS; ++step) {
    // pack EV -> mv1 B-frags (hi/lo)
    short8v Bh[4], Bl[4];
#pragma unroll
    for (int ks = 0; ks < 4; ++ks) {
      frag_u qh, ql;
#pragma unroll
      for (int w = 0; w < 4; ++w) {
        float x0 = evr[ks][2 * w], x1 = evr[ks][2 * w + 1];
        qh.u[w] = pkhi(x0, x1);
        ql.u[w] = pkhi(lof(x0), lof(x1));
      }
      Bh[ks] = qh.s;
      Bl[ks] = ql.s;
    }
    // mv1 (nf-outer, 4-reg acc); packed H goes straight into mv2 B-frags
    frag_u Qh[4], Ql[4];
#pragma unroll
    for (int nf = 0; nf < 8; ++nf) {
      f32x4 acc = aggp[nf];
#pragma unroll
      for (int ks = 0; ks < 4; ++ks) {
        short8v wh = *(const short8v*)&wl[0][0][nf * 4 + ks][lane];
        short8v wo = *(const short8v*)&wl[0][1][nf * 4 + ks][lane];
        acc = __builtin_amdgcn_mfma_f32_16x16x32_bf16(wh, Bh[ks], acc, 0, 0, 0);
        acc = __builtin_amdgcn_mfma_f32_16x16x32_bf16(wh, Bl[ks], acc, 0, 0, 0);
        acc = __builtin_amdgcn_mfma_f32_16x16x32_bf16(wo, Bh[ks], acc, 0, 0, 0);
      }
      float h0 = fmaxf(acc[0], 0.f), h1 = fmaxf(acc[1], 0.f);
      float h2 = fmaxf(acc[2], 0.f), h3 = fmaxf(acc[3], 0.f);
      Qh[nf >> 1].u[2 * (nf & 1) + 0] = pkhi(h0, h1);
      Qh[nf >> 1].u[2 * (nf & 1) + 1] = pkhi(h2, h3);
      Ql[nf >> 1].u[2 * (nf & 1) + 0] = pkhi(lof(h0), lof(h1));
      Ql[nf >> 1].u[2 * (nf & 1) + 1] = pkhi(lof(h2), lof(h3));
    }
    // mv2 (nf-outer, 4-reg acc); output maps 1:1 onto evr via tau
#pragma unroll
    for (int nf = 0; nf < 8; ++nf) {
      f32x4 a2 = {0.f, 0.f, 0.f, 0.f};
#pragma unroll
      for (int ks = 0; ks < 4; ++ks) {
        short8v wh = *(const short8v*)&wl[1][0][nf * 4 + ks][lane];
        short8v wo = *(const short8v*)&wl[1][1][nf * 4 + ks][lane];
        a2 = __builtin_amdgcn_mfma_f32_16x16x32_bf16(wh, Qh[ks].s, a2, 0, 0, 0);
        a2 = __builtin_amdgcn_mfma_f32_16x16x32_bf16(wh, Ql[ks].s, a2, 0, 0, 0);
        a2 = __builtin_amdgcn_mfma_f32_16x16x32_bf16(wo, Qh[ks].s, a2, 0, 0, 0);
      }
      const int kq = nf >> 1, jb = 4 * (nf & 1);
      float4 bv = *(const float4*)&b2s[32 * kq + 8 * g + jb];
      evr[kq][jb + 0] += fmaf(dt, a2[0], bv.x);
      evr[kq][jb + 1] += fmaf(dt, a2[1], bv.y);
      evr[kq][jb + 2] += fmaf(dt, a2[2], bv.z);
      evr[kq][jb + 3] += fmaf(dt, a2[3], bv.w);
    }
  }
  if (ok) {
#pragma unroll
    for (int ks = 0; ks < 4; ++ks) {
      float* p = ev + (size_t)node * DIM + 32 * ks + 8 * g;
      *(float4*)p = make_float4(evr[ks][0], evr[ks][1], evr[ks][2], evr[ks][3]);
      *(float4*)(p + 4) =
          make_float4(evr[ks][4], evr[ks][5], evr[ks][6], evr[ks][7]);
    }
  }
}

extern "C" void kernel_launch(void* const* d_in, const int* in_sizes, int n_in,
                              void* d_out, int out_size, void* d_ws,
                              size_t ws_size, hipStream_t stream) {
  const float* x = (const float*)d_in[0];
  const int* ei = (const int*)d_in[1];
  const float* node_anchor = (const float*)d_in[2];
  const float* W_att = (const float*)d_in[3];
  const float* b_att = (const float*)d_in[4];
  const float* edge_anchor = (const float*)d_in[5];
  const float* W_edge = (const float*)d_in[6];
  const float* b_edge = (const float*)d_in[7];
  const float* W1 = (const float*)d_in[8];
  const float* b1 = (const float*)d_in[9];
  const float* W2 = (const float*)d_in[10];
  const float* b2 = (const float*)d_in[11];

  float* out = (float*)d_out;
  float* ev = out;                     // N*DIM (node_x staged here, then ev)
  float* ep = out + (size_t)NN * DIM;  // E*DIM edge_prompt

  char* ws = (char*)d_ws;
  float* p12 = (float*)(ws);  // N*12 floats = 4.8 MB
  unsigned long long* coeffp =
      (unsigned long long*)(ws + 4800000);   // N*3 u64 = 2.4 MB
  float* Mm = (float*)(ws + 7200000);        // 5*128 floats
  uint4* wpack = (uint4*)(ws + 7202560);     // 128 KB packed W frags

  hipMemsetAsync(coeffp, 0, (size_t)NN * 3 * sizeof(unsigned long long),
                 stream);
  k_prepM<<<NA, DIM, 0, stream>>>(W1, edge_anchor, Mm);
  k_wpack<<<16, 256, 0, stream>>>(W1, W2, wpack);
  k_node<<<2048, 256, 0, stream>>>(x, W_att, b_att, node_anchor, W_edge, b_edge,
                                   ev, p12);
  k_edge2<<<NE / 256, 256, 0, stream>>>(ei, p12, edge_anchor, coeffp, ep);
  k_ode<<<(NN + 127) / 128, 512, 0, stream>>>(coeffp, Mm, wpack, b1, b2, ev);
}

// Round 7
// 1298.944 us; speedup vs baseline: 1.1879x; 1.0857x over previous
//
#include <hip/hip_runtime.h>

#define NN 100000
#define NE 1600000
#define DIM 128
#define NA 5
#define STEPS 5

// fixed-point packing for coeff atomics
#define CSCALE 1048576.0f            // 2^20
#define CINV   9.5367431640625e-07f  // 2^-20

typedef float f32x4 __attribute__((ext_vector_type(4)));
typedef short short8v __attribute__((ext_vector_type(8)));

__device__ __forceinline__ float wsum(float v) {
#pragma unroll
  for (int off = 32; off > 0; off >>= 1) v += __shfl_xor(v, off, 64);
  return v;
}

// pack two f32 into one u32 of 2 bf16 (truncation): low16 = bf16(a), high16 = bf16(b)
__device__ __forceinline__ unsigned pkhi(float a, float b) {
  return __builtin_amdgcn_perm(__float_as_uint(b), __float_as_uint(a),
                               0x07060302u);
}
// residual after bf16 truncation
__device__ __forceinline__ float lof(float x) {
  return x - __uint_as_float(__float_as_uint(x) & 0xffff0000u);
}
// unpack a pkhi word: first value (low16 holds high bits of fp32)
__device__ __forceinline__ float upk0(unsigned u) {
  return __uint_as_float(u << 16);
}
__device__ __forceinline__ float upk1(unsigned u) {
  return __uint_as_float(u & 0xffff0000u);
}

// ---- prep: M = edge_anchor @ W1b.T ----
__global__ __launch_bounds__(128) void k_prepM(
    const float* __restrict__ W1, const float* __restrict__ edge_anchor,
    float* __restrict__ M) {
  const int i = threadIdx.x;
  const int a = blockIdx.x;
  float s = 0.f;
  for (int j = 0; j < DIM; ++j)
    s = fmaf(edge_anchor[a * DIM + j], W1[i * 2 * DIM + DIM + j], s);
  M[a * DIM + i] = s;
}

// ---- pack W1 (A-frags, native) and W2 (A-frags with sigma/tau permutation)
// layout: wp[((mat*2+part)*32 + nf*4+ks)*64 + lane], 16B each (8 bf16)
__global__ __launch_bounds__(256) void k_wpack(
    const float* __restrict__ W1, const float* __restrict__ W2,
    uint4* __restrict__ wp) {
  const int mat = blockIdx.x >> 3, nf = blockIdx.x & 7;
  const int ks = threadIdx.x >> 6, lane = threadIdx.x & 63;
  const int g = lane >> 4, r = lane & 15;
  float v[8];
  if (mat == 0) {
    // A[16nf+r][32ks+8g+j] = W1a[row][col] = W1[row*256 + col]
    const float* src = W1 + (16 * nf + r) * 256 + 32 * ks + 8 * g;
    float4 a = *(const float4*)src;
    float4 b = *(const float4*)(src + 4);
    v[0] = a.x; v[1] = a.y; v[2] = a.z; v[3] = a.w;
    v[4] = b.x; v[5] = b.y; v[6] = b.z; v[7] = b.w;
  } else {
    // A'[16nf+r][32ks+8g+j] = W2[tau(16nf+r)][sigma(32ks+8g+j)]
    // tau = 32*(nf>>1) + 8*(r>>2) + 4*(nf&1) + (r&3)
    // sigma = 32ks + 16*(j>>2) + 4g + (j&3)
    const int trow = 32 * (nf >> 1) + 8 * (r >> 2) + 4 * (nf & 1) + (r & 3);
    const float* src = W2 + trow * 128 + 32 * ks + 4 * g;
    float4 a = *(const float4*)src;         // j=0..3
    float4 b = *(const float4*)(src + 16);  // j=4..7
    v[0] = a.x; v[1] = a.y; v[2] = a.z; v[3] = a.w;
    v[4] = b.x; v[5] = b.y; v[6] = b.z; v[7] = b.w;
  }
  unsigned h[4], l[4];
#pragma unroll
  for (int w = 0; w < 4; ++w) {
    h[w] = pkhi(v[2 * w], v[2 * w + 1]);
    l[w] = pkhi(lof(v[2 * w]), lof(v[2 * w + 1]));
  }
  wp[((mat * 2 + 0) * 32 + nf * 4 + ks) * 64 + lane] =
      make_uint4(h[0], h[1], h[2], h[3]);
  wp[((mat * 2 + 1) * 32 + nf * 4 + ks) * 64 + lane] =
      make_uint4(l[0], l[1], l[2], l[3]);
}

// ---- node pre-pass: att softmax + node_x, and p1/p2 edge projections ----
__global__ __launch_bounds__(256) void k_node(
    const float* __restrict__ x, const float* __restrict__ W_att,
    const float* __restrict__ b_att, const float* __restrict__ node_anchor,
    const float* __restrict__ W_edge, const float* __restrict__ b_edge,
    float* __restrict__ node_x, float* __restrict__ p12) {
  const int wid = threadIdx.x >> 6, lane = threadIdx.x & 63;
  const int d0 = lane << 1;
  float wa0[NA], wa1[NA], we10[NA], we11[NA], we20[NA], we21[NA];
  float na0[NA], na1[NA], ba[NA], be[NA];
#pragma unroll
  for (int a = 0; a < NA; ++a) {
    wa0[a] = W_att[a * DIM + d0];
    wa1[a] = W_att[a * DIM + d0 + 1];
    we10[a] = W_edge[a * 2 * DIM + d0];
    we11[a] = W_edge[a * 2 * DIM + d0 + 1];
    we20[a] = W_edge[a * 2 * DIM + DIM + d0];
    we21[a] = W_edge[a * 2 * DIM + DIM + d0 + 1];
    na0[a] = node_anchor[a * DIM + d0];
    na1[a] = node_anchor[a * DIM + d0 + 1];
    ba[a] = b_att[a];
    be[a] = b_edge[a];
  }
  const int stride = gridDim.x << 2;
  for (int n = (blockIdx.x << 2) + wid; n < NN; n += stride) {
    float2 xv = *(const float2*)(x + (size_t)n * DIM + d0);
    float att[NA], p1[NA], p2[NA];
#pragma unroll
    for (int a = 0; a < NA; ++a) {
      att[a] = wsum(xv.x * wa0[a] + xv.y * wa1[a]) + ba[a];
      p1[a] = wsum(xv.x * we10[a] + xv.y * we11[a]) + be[a];
      p2[a] = wsum(xv.x * we20[a] + xv.y * we21[a]);
    }
    float m = fmaxf(fmaxf(fmaxf(att[0], att[1]), fmaxf(att[2], att[3])), att[4]);
    float s = 0.f;
#pragma unroll
    for (int a = 0; a < NA; ++a) { att[a] = expf(att[a] - m); s += att[a]; }
    float inv = 1.f / s;
    float2 nx = xv;
#pragma unroll
    for (int a = 0; a < NA; ++a) {
      float w = att[a] * inv;
      nx.x = fmaf(w, na0[a], nx.x);
      nx.y = fmaf(w, na1[a], nx.y);
    }
    *(float2*)(node_x + (size_t)n * DIM + d0) = nx;
    if (lane < NA) {
      float v1 = p1[0], v2 = p2[0];
#pragma unroll
      for (int a = 1; a < NA; ++a)
        if (lane == a) { v1 = p1[a]; v2 = p2[a]; }
      p12[(size_t)n * 12 + lane] = v1;
      p12[(size_t)n * 12 + 6 + lane] = v2;
    }
  }
}

__device__ __forceinline__ void edge_b(const float* __restrict__ p12, int src,
                                       int dst, float* __restrict__ b) {
  float4 q1 = *(const float4*)(p12 + (size_t)src * 12);
  float p14 = p12[(size_t)src * 12 + 4];
  float2 r0 = *(const float2*)(p12 + (size_t)dst * 12 + 6);
  float2 r1 = *(const float2*)(p12 + (size_t)dst * 12 + 8);
  float p24 = p12[(size_t)dst * 12 + 10];
  float l[NA] = {q1.x + r0.x, q1.y + r0.y, q1.z + r1.x, q1.w + r1.y,
                 p14 + p24};
#pragma unroll
  for (int a = 0; a < NA; ++a) l[a] = l[a] >= 0.f ? l[a] : 0.01f * l[a];
  float m = fmaxf(fmaxf(fmaxf(l[0], l[1]), fmaxf(l[2], l[3])), l[4]);
  float s = 0.f;
#pragma unroll
  for (int a = 0; a < NA; ++a) { l[a] = expf(l[a] - m); s += l[a]; }
  float inv = 1.f / s;
#pragma unroll
  for (int a = 0; a < NA; ++a) b[a] = l[a] * inv;
}

// ---- fused edge pass: coeff atomics + edge_prompt stream-out.
// No __syncthreads (wave-private LDS slice) so atomic latency hides under
// the store stream and we make a single pass over ei/p12.
__global__ __launch_bounds__(256) void k_edge2(
    const int* __restrict__ ei, const float* __restrict__ p12,
    const float* __restrict__ edge_anchor,
    unsigned long long* __restrict__ coeffp, float* __restrict__ ep) {
  __shared__ float bs[4][64][8];
  const int t = threadIdx.x;
  const int w = t >> 6, lane = t & 63;
  const int e = blockIdx.x * 256 + t;
  {
    const int src = ei[e], dst = ei[NE + e];
    float b[NA];
    edge_b(p12, src, dst, b);
    unsigned q[NA];
#pragma unroll
    for (int a = 0; a < NA; ++a) q[a] = (unsigned)fmaf(b[a], CSCALE, 0.5f);
    unsigned long long p01 =
        (unsigned long long)q[0] | ((unsigned long long)q[1] << 32);
    unsigned long long p23 =
        (unsigned long long)q[2] | ((unsigned long long)q[3] << 32);
    unsigned long long p4 = (unsigned long long)q[4];
    atomicAdd(coeffp + (size_t)src * 3 + 0, p01);
    atomicAdd(coeffp + (size_t)src * 3 + 1, p23);
    atomicAdd(coeffp + (size_t)src * 3 + 2, p4);
    atomicAdd(coeffp + (size_t)dst * 3 + 0, p01);
    atomicAdd(coeffp + (size_t)dst * 3 + 1, p23);
    atomicAdd(coeffp + (size_t)dst * 3 + 2, p4);
    // wave-private LDS slice: same-wave DS ops are in-order, no barrier
    *(float4*)&bs[w][lane][0] = make_float4(b[0], b[1], b[2], b[3]);
    bs[w][lane][4] = b[4];
  }
  // 2 edges per iter, float4 (1 KB/wave/instruction) NT stores
  const int esub = lane >> 5, d0 = (lane & 31) << 2;
  float4 ea4[NA];
#pragma unroll
  for (int a = 0; a < NA; ++a)
    ea4[a] = *(const float4*)(edge_anchor + a * DIM + d0);
  const size_t ebase = (size_t)blockIdx.x * 256 + ((size_t)w << 6);
#pragma unroll 2
  for (int k = 0; k < 32; ++k) {
    const int el = 2 * k + esub;
    float4 c = *(const float4*)&bs[w][el][0];
    float c4 = bs[w][el][4];
    f32x4 v;
#pragma unroll
    for (int i = 0; i < 4; ++i) {
      float s = c.x * ((const float*)&ea4[0])[i];
      s = fmaf(c.y, ((const float*)&ea4[1])[i], s);
      s = fmaf(c.z, ((const float*)&ea4[2])[i], s);
      s = fmaf(c.w, ((const float*)&ea4[3])[i], s);
      s = fmaf(c4, ((const float*)&ea4[4])[i], s);
      v[i] = s;
    }
    __builtin_nontemporal_store(v, (f32x4*)(ep + (ebase + el) * DIM + d0));
  }
}

// ---- ODE via MFMA, split-bf16. EV state lives entirely in the packed hi/lo
// B-frags Bh/Bl (hi+lo splits fp32 near-losslessly); mv2's per-nf output
// updates 2 u-words of Bh[kq]/Bl[kq] in place (compile-time slots). This
// keeps the live set ~125 VGPRs -> no spill at any launch-bounds cap.
__global__ __launch_bounds__(512, 1) void k_ode(
    const unsigned long long* __restrict__ coeffp, const float* __restrict__ M,
    const uint4* __restrict__ wp, const float* __restrict__ b1,
    const float* __restrict__ b2, float* __restrict__ ev) {
  __shared__ uint4 wl[2][2][32][64];  // [mat][part][nf*4+ks][lane] = 128 KB
  __shared__ float b2s[DIM];          // dt * b2
  const int tid = threadIdx.x;
  {
    uint4* dst = &wl[0][0][0][0];
#pragma unroll
    for (int i = 0; i < 16; ++i) dst[i * 512 + tid] = wp[i * 512 + tid];
  }
  if (tid < DIM) b2s[tid] = (1.f / STEPS) * b2[tid];
  const int wid = tid >> 6, lane = tid & 63;
  const int g = lane >> 4, r = lane & 15;
  const int node = blockIdx.x * 128 + wid * 16 + r;
  const bool ok = node < NN;

  typedef union { unsigned u[4]; short8v s; } frag_u;
  // EV state, packed: Bh/Bl[ks].u[w] hold EV[node][32ks+8g+{2w,2w+1}] hi/lo
  frag_u Bh[4], Bl[4];
#pragma unroll
  for (int ks = 0; ks < 4; ++ks) {
    float4 a = make_float4(0.f, 0.f, 0.f, 0.f), b = a;
    if (ok) {
      const float* p = ev + (size_t)node * DIM + 32 * ks + 8 * g;
      a = *(const float4*)p;
      b = *(const float4*)(p + 4);
    }
    Bh[ks].u[0] = pkhi(a.x, a.y); Bl[ks].u[0] = pkhi(lof(a.x), lof(a.y));
    Bh[ks].u[1] = pkhi(a.z, a.w); Bl[ks].u[1] = pkhi(lof(a.z), lof(a.w));
    Bh[ks].u[2] = pkhi(b.x, b.y); Bl[ks].u[2] = pkhi(lof(b.x), lof(b.y));
    Bh[ks].u[3] = pkhi(b.z, b.w); Bl[ks].u[3] = pkhi(lof(b.z), lof(b.w));
  }
  // agg_proj in C layout: aggp[nf][i] = b1[col] + sum_a c[a]*M[a][col],
  // col = 16nf + 4g + i
  f32x4 aggp[8];
  {
    float c[NA] = {0.f, 0.f, 0.f, 0.f, 0.f};
    if (ok) {
      unsigned long long v0 = coeffp[(size_t)node * 3 + 0];
      unsigned long long v1 = coeffp[(size_t)node * 3 + 1];
      unsigned long long v2 = coeffp[(size_t)node * 3 + 2];
      c[0] = (float)(unsigned)v0 * CINV;
      c[1] = (float)(unsigned)(v0 >> 32) * CINV;
      c[2] = (float)(unsigned)v1 * CINV;
      c[3] = (float)(unsigned)(v1 >> 32) * CINV;
      c[4] = (float)(unsigned)v2 * CINV;
    }
#pragma unroll
    for (int nf = 0; nf < 8; ++nf) {
      float4 bb = *(const float4*)(b1 + 16 * nf + 4 * g);
      f32x4 s = {bb.x, bb.y, bb.z, bb.w};
#pragma unroll
      for (int a = 0; a < NA; ++a) {
        float4 mm = *(const float4*)(M + a * DIM + 16 * nf + 4 * g);
        s[0] = fmaf(c[a], mm.x, s[0]);
        s[1] = fmaf(c[a], mm.y, s[1]);
        s[2] = fmaf(c[a], mm.z, s[2]);
        s[3] = fmaf(c[a], mm.w, s[3]);
      }
      aggp[nf] = s;
    }
  }
  __syncthreads();
  const float dt = 1.f / STEPS;

#pragma unroll 1
  for (int step = 0; step < STEPS; ++step) {
    // mv1 (nf-outer, 4-reg acc); packed H goes straight into mv2 B-frags
    frag_u Qh[4], Ql[4];
#pragma unroll
    for (int nf = 0; nf < 8; ++nf) {
      f32x4 acc = aggp[nf];
#pragma unroll
      for (int ks = 0; ks < 4; ++ks) {
        short8v wh = *(const short8v*)&wl[0][0][nf * 4 + ks][lane];
        short8v wo = *(const short8v*)&wl[0][1][nf * 4 + ks][lane];
        acc = __builtin_amdgcn_mfma_f32_16x16x32_bf16(wh, Bh[ks].s, acc, 0, 0, 0);
        acc = __builtin_amdgcn_mfma_f32_16x16x32_bf16(wh, Bl[ks].s, acc, 0, 0, 0);
        acc = __builtin_amdgcn_mfma_f32_16x16x32_bf16(wo, Bh[ks].s, acc, 0, 0, 0);
      }
      float h0 = fmaxf(acc[0], 0.f), h1 = fmaxf(acc[1], 0.f);
      float h2 = fmaxf(acc[2], 0.f), h3 = fmaxf(acc[3], 0.f);
      Qh[nf >> 1].u[2 * (nf & 1) + 0] = pkhi(h0, h1);
      Qh[nf >> 1].u[2 * (nf & 1) + 1] = pkhi(h2, h3);
      Ql[nf >> 1].u[2 * (nf & 1) + 0] = pkhi(lof(h0), lof(h1));
      Ql[nf >> 1].u[2 * (nf & 1) + 1] = pkhi(lof(h2), lof(h3));
    }
    // mv2 (nf-outer, 4-reg acc); per-nf output updates Bh/Bl[kq] in place
#pragma unroll
    for (int nf = 0; nf < 8; ++nf) {
      f32x4 a2 = {0.f, 0.f, 0.f, 0.f};
#pragma unroll
      for (int ks = 0; ks < 4; ++ks) {
        short8v wh = *(const short8v*)&wl[1][0][nf * 4 + ks][lane];
        short8v wo = *(const short8v*)&wl[1][1][nf * 4 + ks][lane];
        a2 = __builtin_amdgcn_mfma_f32_16x16x32_bf16(wh, Qh[ks].s, a2, 0, 0, 0);
        a2 = __builtin_amdgcn_mfma_f32_16x16x32_bf16(wh, Ql[ks].s, a2, 0, 0, 0);
        a2 = __builtin_amdgcn_mfma_f32_16x16x32_bf16(wo, Qh[ks].s, a2, 0, 0, 0);
      }
      const int kq = nf >> 1, jb = 4 * (nf & 1), w0 = 2 * (nf & 1);
      float4 bv = *(const float4*)&b2s[32 * kq + 8 * g + jb];
      {
        unsigned uh = Bh[kq].u[w0], ul = Bl[kq].u[w0];
        float n0 = upk0(uh) + upk0(ul) + fmaf(dt, a2[0], bv.x);
        float n1 = upk1(uh) + upk1(ul) + fmaf(dt, a2[1], bv.y);
        Bh[kq].u[w0] = pkhi(n0, n1);
        Bl[kq].u[w0] = pkhi(lof(n0), lof(n1));
      }
      {
        unsigned uh = Bh[kq].u[w0 + 1], ul = Bl[kq].u[w0 + 1];
        float n2 = upk0(uh) + upk0(ul) + fmaf(dt, a2[2], bv.z);
        float n3 = upk1(uh) + upk1(ul) + fmaf(dt, a2[3], bv.w);
        Bh[kq].u[w0 + 1] = pkhi(n2, n3);
        Bl[kq].u[w0 + 1] = pkhi(lof(n2), lof(n3));
      }
    }
  }
  if (ok) {
#pragma unroll
    for (int ks = 0; ks < 4; ++ks) {
      float* p = ev + (size_t)node * DIM + 32 * ks + 8 * g;
      float4 o0, o1;
      o0.x = upk0(Bh[ks].u[0]) + upk0(Bl[ks].u[0]);
      o0.y = upk1(Bh[ks].u[0]) + upk1(Bl[ks].u[0]);
      o0.z = upk0(Bh[ks].u[1]) + upk0(Bl[ks].u[1]);
      o0.w = upk1(Bh[ks].u[1]) + upk1(Bl[ks].u[1]);
      o1.x = upk0(Bh[ks].u[2]) + upk0(Bl[ks].u[2]);
      o1.y = upk1(Bh[ks].u[2]) + upk1(Bl[ks].u[2]);
      o1.z = upk0(Bh[ks].u[3]) + upk0(Bl[ks].u[3]);
      o1.w = upk1(Bh[ks].u[3]) + upk1(Bl[ks].u[3]);
      *(float4*)p = o0;
      *(float4*)(p + 4) = o1;
    }
  }
}

extern "C" void kernel_launch(void* const* d_in, const int* in_sizes, int n_in,
                              void* d_out, int out_size, void* d_ws,
                              size_t ws_size, hipStream_t stream) {
  const float* x = (const float*)d_in[0];
  const int* ei = (const int*)d_in[1];
  const float* node_anchor = (const float*)d_in[2];
  const float* W_att = (const float*)d_in[3];
  const float* b_att = (const float*)d_in[4];
  const float* edge_anchor = (const float*)d_in[5];
  const float* W_edge = (const float*)d_in[6];
  const float* b_edge = (const float*)d_in[7];
  const float* W1 = (const float*)d_in[8];
  const float* b1 = (const float*)d_in[9];
  const float* W2 = (const float*)d_in[10];
  const float* b2 = (const float*)d_in[11];

  float* out = (float*)d_out;
  float* ev = out;                     // N*DIM (node_x staged here, then ev)
  float* ep = out + (size_t)NN * DIM;  // E*DIM edge_prompt

  char* ws = (char*)d_ws;
  float* p12 = (float*)(ws);  // N*12 floats = 4.8 MB
  unsigned long long* coeffp =
      (unsigned long long*)(ws + 4800000);   // N*3 u64 = 2.4 MB
  float* Mm = (float*)(ws + 7200000);        // 5*128 floats
  uint4* wpack = (uint4*)(ws + 7202560);     // 128 KB packed W frags

  hipMemsetAsync(coeffp, 0, (size_t)NN * 3 * sizeof(unsigned long long),
                 stream);
  k_prepM<<<NA, DIM, 0, stream>>>(W1, edge_anchor, Mm);
  k_wpack<<<16, 256, 0, stream>>>(W1, W2, wpack);
  k_node<<<2048, 256, 0, stream>>>(x, W_att, b_att, node_anchor, W_edge, b_edge,
                                   ev, p12);
  k_edge2<<<NE / 256, 256, 0, stream>>>(ei, p12, edge_anchor, coeffp, ep);
  k_ode<<<(NN + 127) / 128, 512, 0, stream>>>(coeffp, Mm, wpack, b1, b2, ev);
}